// Round 1
// baseline (134.723 us; speedup 1.0000x reference)
//
#include <hip/hip_runtime.h>
#include <math.h>

typedef _Float16 half8  __attribute__((ext_vector_type(8)));
typedef _Float16 half4v __attribute__((ext_vector_type(4)));
typedef float    floatx4 __attribute__((ext_vector_type(4)));

#define NTOK   4096      // 128*32 tokens per side
#define DDIM   256
#define LPITCH 72        // 64 + 8 halves (16B pad) -> <=2-way LDS bank aliasing (free)

// ---------------------------------------------------------------- fp32 -> fp16
__global__ void cvt_fp16(const float* __restrict__ src, _Float16* __restrict__ dst) {
    int i = (blockIdx.x * blockDim.x + threadIdx.x) * 4;
    float4 v = *(const float4*)(src + i);
    half4v h;
    h[0] = (_Float16)v.x; h[1] = (_Float16)v.y; h[2] = (_Float16)v.z; h[3] = (_Float16)v.w;
    *(half4v*)(dst + i) = h;
}

// ------------------------------------------------- per-token vMF scalar stats
// idx < 4096 : q tokens -> Apq, kqc, uq, entropy(out)
// idx >= 4096: t tokens -> At, ktc, vt
// log_bessel_i(v,x) = lse_k[(2k+v)ln(x/2) - lgamma(k+1) - lgamma(k+v+1)], 50 terms
// (exactly the reference's truncation). nu=127, nu+1=128. Running log-gamma sums
// accumulated in double (values reach ~700; float accumulation would cost ~1e-3).
__global__ void vmf_stats(const float* __restrict__ kq, const float* __restrict__ kt,
                          float* __restrict__ Apq, float* __restrict__ kqc, float* __restrict__ uq,
                          float* __restrict__ At,  float* __restrict__ ktc, float* __restrict__ vt,
                          float* __restrict__ ent_out) {
    int idx = blockIdx.x * blockDim.x + threadIdx.x;
    bool isQ = idx < NTOK;
    int t = isQ ? idx : idx - NTOK;
    float kap = fmaxf(isQ ? kq[t] : kt[t], 1e-6f);
    float lx = logf(0.5f * kap);

    double lgA = 0.0;               // lgamma(k+1)
    double lgB = lgamma(128.0);     // lgamma(k+128)
    float m0 = -INFINITY, s0 = 0.f; // lse for nu=127
    float m1 = -INFINITY, s1 = 0.f; // lse for nu+1=128
    for (int k = 0; k < 50; ++k) {
        double lgBn = lgB + log((double)(k + 128));          // lgamma(k+129)
        float lc0 = (float)(2*k + 127) * lx - (float)(lgA + lgB);
        float lc1 = (float)(2*k + 128) * lx - (float)(lgA + lgBn);
        if (lc0 > m0) { s0 = s0 * expf(m0 - lc0) + 1.f; m0 = lc0; } else s0 += expf(lc0 - m0);
        if (lc1 > m1) { s1 = s1 * expf(m1 - lc1) + 1.f; m1 = lc1; } else s1 += expf(lc1 - m1);
        lgB = lgBn;
        lgA += log((double)(k + 1));
    }
    float logI0 = m0 + logf(s0);    // log I_127(kap)
    float logI1 = m1 + logf(s1);    // log I_128(kap)

    float A = expf(fminf(fmaxf(logI1 - logI0, -60.f), 0.f));
    A = fminf(fmaxf(A, 1e-8f), 1.f - 1e-6f);
    // logC = nu*log(k) - (d/2)*log(2pi) - logI0 ; 128*log(2pi) = 235.24826449839620...
    float logC = 127.f * logf(kap) - 235.2482644983962f - logI0;

    if (isQ) {
        Apq[t] = A; kqc[t] = kap; uq[t] = -0.5f * A * kap;
        ent_out[t] = -logC - kap * A;
    } else {
        At[t] = A; ktc[t] = kap; vt[t] = -0.5f * A * kap;
    }
}

// --------------------------------------- token weights: softmax(-2*entropy) over q
__global__ void token_weights(const float* __restrict__ ent, float* __restrict__ wq) {
    int b = blockIdx.x, lane = threadIdx.x;
    float e = (lane < 32) ? -2.0f * ent[b * 32 + lane] : -INFINITY;
    float m = e;
    #pragma unroll
    for (int off = 1; off < 64; off <<= 1) m = fmaxf(m, __shfl_xor(m, off, 64));
    float p = (lane < 32) ? expf(e - m) : 0.f;
    float s = p;
    #pragma unroll
    for (int off = 1; off < 64; off <<= 1) s += __shfl_xor(s, off, 64);
    if (lane < 32) wq[b * 32 + lane] = p / s;
}

// --------------------------------------------------- fused GEMM + vMF epilogue
// C[4096,4096] = Qh * Th^T, 128x128 tile per block, 4 waves each own a 64x64
// quadrant (4x4 grid of 16x16x32 f16 MFMA). Epilogue per (b,n) 32x32 sub-block:
// score = u[row]+v[col]+0.5*(Ap[row]*kt[col]+At[col]*kq[row])*sim ; max over 32
// cols (reg-local + 16-lane butterfly) ; weighted sum over 32 rows -> score_global.
__global__ void __launch_bounds__(256)
gemm_score(const _Float16* __restrict__ Qh, const _Float16* __restrict__ Th,
           const float* __restrict__ Apq, const float* __restrict__ kqc,
           const float* __restrict__ uq,  const float* __restrict__ wq,
           const float* __restrict__ At,  const float* __restrict__ ktc,
           const float* __restrict__ vt,  float* __restrict__ score_out) {
    __shared__ _Float16 Qs[128 * LPITCH];
    __shared__ _Float16 Ts[128 * LPITCH];
    int tid = threadIdx.x;
    int lane = tid & 63, wave = tid >> 6;
    int wr = wave >> 1, wc = wave & 1;          // wave quadrant (row, col)
    int bx = blockIdx.x, by = blockIdx.y;       // bx: n-tiles, by: bq-tiles

    floatx4 acc[4][4];
    #pragma unroll
    for (int i = 0; i < 4; ++i)
        #pragma unroll
        for (int j = 0; j < 4; ++j)
            acc[i][j] = (floatx4){0.f, 0.f, 0.f, 0.f};

    int l15 = lane & 15, lq = lane >> 4;

    for (int kk = 0; kk < 4; ++kk) {            // K = 256 in 4 chunks of 64
        __syncthreads();
        #pragma unroll
        for (int it = 0; it < 4; ++it) {        // stage 128x64 halves per tile
            int s = it * 256 + tid;
            int r = s >> 3, c = s & 7;          // row, 16B-chunk within row
            *(uint4*)(Qs + r * LPITCH + c * 8) =
                *(const uint4*)(Qh + (size_t)(by * 128 + r) * DDIM + kk * 64 + c * 8);
            *(uint4*)(Ts + r * LPITCH + c * 8) =
                *(const uint4*)(Th + (size_t)(bx * 128 + r) * DDIM + kk * 64 + c * 8);
        }
        __syncthreads();
        #pragma unroll
        for (int ks = 0; ks < 2; ++ks) {        // two K=32 MFMA steps per chunk
            half8 a[4], b[4];
            int ko = ks * 32 + lq * 8;
            #pragma unroll
            for (int i = 0; i < 4; ++i)
                a[i] = *(const half8*)(Qs + (wr * 64 + i * 16 + l15) * LPITCH + ko);
            #pragma unroll
            for (int j = 0; j < 4; ++j)
                b[j] = *(const half8*)(Ts + (wc * 64 + j * 16 + l15) * LPITCH + ko);
            #pragma unroll
            for (int i = 0; i < 4; ++i)
                #pragma unroll
                for (int j = 0; j < 4; ++j)
                    acc[i][j] = __builtin_amdgcn_mfma_f32_16x16x32_f16(a[i], b[j], acc[i][j], 0, 0, 0);
        }
    }

    // ---- epilogue: 4 (b,n) pairs per wave (2x2), each a 32x32 score block
    int colbase = bx * 128 + wc * 64 + l15;     // + j*16 -> global t-token col
    int rowbase = by * 128 + wr * 64 + lq * 4;  // + i*16 + reg -> global q-token row
    #pragma unroll
    for (int bi = 0; bi < 2; ++bi) {
        #pragma unroll
        for (int bj = 0; bj < 2; ++bj) {
            float part = 0.f;
            #pragma unroll
            for (int ii = 0; ii < 2; ++ii) {
                int i  = bi * 2 + ii;
                int rg = rowbase + i * 16;
                float mx[4] = {-INFINITY, -INFINITY, -INFINITY, -INFINITY};
                #pragma unroll
                for (int jj = 0; jj < 2; ++jj) {
                    int j  = bj * 2 + jj;
                    int cg = colbase + j * 16;
                    float at_ = At[cg], kt_ = ktc[cg], v_ = vt[cg];
                    floatx4 sim = acc[i][j];
                    #pragma unroll
                    for (int rr = 0; rr < 4; ++rr) {
                        float sc = uq[rg + rr] + v_ +
                                   0.5f * (Apq[rg + rr] * kt_ + at_ * kqc[rg + rr]) * sim[rr];
                        mx[rr] = fmaxf(mx[rr], sc);
                    }
                }
                #pragma unroll
                for (int msk = 1; msk <= 8; msk <<= 1)
                    #pragma unroll
                    for (int rr = 0; rr < 4; ++rr)
                        mx[rr] = fmaxf(mx[rr], __shfl_xor(mx[rr], msk, 64));
                if (l15 == 0) {
                    #pragma unroll
                    for (int rr = 0; rr < 4; ++rr)
                        part += wq[rg + rr] * mx[rr];   // rows i*16 + lq*4 + rr
                }
            }
            part += __shfl_xor(part, 16, 64);
            part += __shfl_xor(part, 32, 64);
            if (lane == 0) {
                int b = by * 4 + wr * 2 + bi;
                int n = bx * 4 + wc * 2 + bj;
                score_out[b * 128 + n] = part;
            }
        }
    }
}

// ------------------------------------------- logits, log-softmax over n, loss
__global__ void softmax_loss(const float* __restrict__ score, const float* __restrict__ temp_p,
                             float* __restrict__ logits, float* __restrict__ loss) {
    int b = blockIdx.x, lane = threadIdx.x;
    float temp = fmaxf(temp_p[0], 1e-6f);
    float l0 = score[b * 128 + lane] / temp;
    float l1 = score[b * 128 + 64 + lane] / temp;
    logits[b * 128 + lane] = l0;
    logits[b * 128 + 64 + lane] = l1;
    float m = fmaxf(l0, l1);
    #pragma unroll
    for (int off = 1; off < 64; off <<= 1) m = fmaxf(m, __shfl_xor(m, off, 64));
    float s = expf(l0 - m) + expf(l1 - m);
    #pragma unroll
    for (int off = 1; off < 64; off <<= 1) s += __shfl_xor(s, off, 64);
    if (lane == 0) {
        float lse = m + logf(s);
        float diag = score[b * 128 + b] / temp;
        atomicAdd(loss, (lse - diag) * (1.0f / 128.0f));
    }
}

// ---------------------------------------------------------------------- launch
extern "C" void kernel_launch(void* const* d_in, const int* in_sizes, int n_in,
                              void* d_out, int out_size, void* d_ws, size_t ws_size,
                              hipStream_t stream) {
    const float* q    = (const float*)d_in[0];   // (128,32,256)
    const float* kq   = (const float*)d_in[1];   // (128,32)
    const float* t    = (const float*)d_in[2];   // (128,32,256)
    const float* kt   = (const float*)d_in[3];   // (128,32)
    const float* temp = (const float*)d_in[4];   // scalar

    float* out    = (float*)d_out;
    float* loss   = out;                 // [1]
    float* logits = out + 1;             // [128*128]
    float* score  = out + 1 + 16384;     // [128*128]
    float* ent    = out + 1 + 32768;     // [128*32]

    char* ws = (char*)d_ws;              // usage: 2MB + 2MB + 112KB
    _Float16* Qh = (_Float16*)(ws);
    _Float16* Th = (_Float16*)(ws + (1 << 21));
    float* stats = (float*)(ws + (1 << 22));
    float *Apq = stats,          *kqc = stats + 4096, *uq = stats + 8192,
          *wq  = stats + 12288,  *At  = stats + 16384, *ktc = stats + 20480,
          *vt  = stats + 24576;

    hipMemsetAsync(d_out, 0, sizeof(float), stream);   // zero loss accumulator
    cvt_fp16<<<1024, 256, 0, stream>>>(q, Qh);
    cvt_fp16<<<1024, 256, 0, stream>>>(t, Th);
    vmf_stats<<<32, 256, 0, stream>>>(kq, kt, Apq, kqc, uq, At, ktc, vt, ent);
    token_weights<<<128, 64, 0, stream>>>(ent, wq);
    dim3 g(32, 32);
    gemm_score<<<g, 256, 0, stream>>>(Qh, Th, Apq, kqc, uq, wq, At, ktc, vt, score);
    softmax_loss<<<128, 64, 0, stream>>>(score, temp, logits, loss);
}